// Round 8
// baseline (317.944 us; speedup 1.0000x reference)
//
#include <hip/hip_runtime.h>
#include <math.h>

#define NBINS 182
#define NB 128   // batch

typedef unsigned short u16;
typedef __attribute__((ext_vector_type(8))) short short8;   // 8 bf16 (4 VGPRs)
typedef __attribute__((ext_vector_type(4))) float f32x4;    // MFMA accumulator

__device__ __forceinline__ u16 f2bf(float f) {
    union { float f; unsigned u; } v; v.f = f;
    unsigned r = v.u + 0x7FFF + ((v.u >> 16) & 1);   // RNE
    return (u16)(r >> 16);
}
__device__ __forceinline__ float bf2f(u16 u) {
    union { unsigned u; float f; } v; v.u = ((unsigned)u) << 16;
    return v.f;
}
__device__ __forceinline__ short8 negbf(short8 v) {
    short8 r;
#pragma unroll
    for (int i = 0; i < 8; ++i) r[i] = v[i] ^ (short)0x8000;
    return r;
}

// (int)sqrtf is EXACT here: d2 <= 32768, non-square integers are >= 2.7e-3
// from an integer sqrt (350x float ulp at 181).
__device__ __forceinline__ int radial_bin(int dx, int dy) {
    return (int)sqrtf((float)(dx * dx + dy * dy));
}

// ---------------------------------------------------------------------------
// prep: small setup launch.
//   [0,256)    build_M row j (fp64 accum -> M fp32 + A1 bf16)
//   [256,512)  nr partial histogram -> nrpart[bin][row] (transposed)
//   [512,544)  zero tbin + cnt
// ---------------------------------------------------------------------------
__global__ __launch_bounds__(256) void prep(float* __restrict__ M_re,
                                            float* __restrict__ M_im,
                                            u16* __restrict__ A1,
                                            float* __restrict__ nrpart,
                                            float* __restrict__ tbin,
                                            int* __restrict__ cnt) {
    __shared__ double ctab[1024];
    __shared__ double stab[1024];
    __shared__ float s[NBINS];
    int blk = blockIdx.x;
    int t = threadIdx.x;

    if (blk < 256) {             // ---- build_M ----
        for (int i = t; i < 1024; i += 256) {
            double a = 3.14159265358979323846 * (double)i / 512.0;
            ctab[i] = cos(a);
            stab[i] = sin(a);
        }
        __syncthreads();
        int j = blk;
        int w = t;
        double re = 0.0, im = 0.0;
        int tw = 2 * w + 1;
        for (int k = 0; k < 256; ++k) {
            int e = (4 * j * k) & 1023;
            int m = (tw * k) & 1023;
            double cw = 2.0 * ctab[m];
            re += ctab[e] * cw;
            im -= stab[e] * cw;
        }
        M_re[j * 256 + w] = (float)re;
        M_im[j * 256 + w] = (float)im;
        A1[j * 256 + w] = f2bf((float)re);
        A1[(j + 256) * 256 + w] = f2bf((float)im);
    } else if (blk < 512) {      // ---- nr partial histogram, row i ----
        int i = blk - 256;
        if (t < NBINS) s[t] = 0.0f;
        __syncthreads();
        int bin = radial_bin(t - 128, i - 128);
        atomicAdd(&s[bin], 1.0f);
        __syncthreads();
        if (t < NBINS) nrpart[t * 256 + i] = s[t];   // [bin][row]
    } else {                     // ---- zero tbin + cnt ----
        int idx = (blk - 512) * 256 + t;
        for (int i = idx; i < NB * NBINS; i += 32 * 256) tbin[i] = 0.0f;
        if (blk == 512 && t < NB) cnt[t] = 0;
    }
}

// ---------------------------------------------------------------------------
// Stage 1 (MFMA, gray fused): C[r][h] = sum_w A1[r,w] * luma(x)[b,h,w]
// r in [0,512): r<256 -> Tt_re row r, else Tt_im row r-256. Output bf16.
// Block: 128x128 tile, 256 thr, wave = 64x64 (4x4 of 16x16x32). K=256, BK=32.
// B-staging computes luma from the 3 x-channels on the fly (x is L3-resident;
// no G materialization).
// ---------------------------------------------------------------------------
__global__ __launch_bounds__(256) void s1(const float* __restrict__ x,
                                          const u16* __restrict__ A1,
                                          u16* __restrict__ Tt_re,
                                          u16* __restrict__ Tt_im) {
    __shared__ u16 As[128 * 40];   // row stride 40 (16B-aligned, conflict-free)
    __shared__ u16 Bs[128 * 40];
    int b = blockIdx.z;
    int r0 = blockIdx.y * 128;    // 0,128,256,384
    int h0 = blockIdx.x * 128;    // 0,128
    int t = threadIdx.x;
    int lane = t & 63, wv = t >> 6;
    int wr = (wv >> 1) * 64;
    int wc = (wv & 1) * 64;
    int fr = lane & 15;
    int fk = (lane >> 4) << 3;

    f32x4 acc[4][4];
#pragma unroll
    for (int i = 0; i < 4; ++i)
#pragma unroll
        for (int j = 0; j < 4; ++j) acc[i][j] = (f32x4){0.f, 0.f, 0.f, 0.f};

    const u16* Ap = A1 + (size_t)r0 * 256;
    const float* xb = x + (size_t)b * 196608 + (size_t)h0 * 256;

    for (int kk = 0; kk < 256; kk += 32) {
        // A tile: 128 rows x 32 cols bf16
#pragma unroll
        for (int c = t; c < 512; c += 256) {
            int row = c >> 2, off = (c & 3) << 3;
            *(uint4*)&As[row * 40 + off] =
                *(const uint4*)(Ap + (size_t)row * 256 + kk + off);
        }
        // B tile: luma of x, 128 rows x 32 cols -> bf16
#pragma unroll
        for (int it = 0; it < 4; ++it) {
            int id = t + it * 256;          // 0..1023
            int row = id >> 3;              // 0..127
            int cg = (id & 7) * 4;          // 0,4,..,28
            const float* p = xb + (size_t)row * 256 + kk + cg;
            float4 r = *(const float4*)p;
            float4 g = *(const float4*)(p + 65536);
            float4 bl = *(const float4*)(p + 131072);
            float g0 = 0.2989f * r.x + 0.587f * g.x + 0.114f * bl.x;
            float g1 = 0.2989f * r.y + 0.587f * g.y + 0.114f * bl.y;
            float g2 = 0.2989f * r.z + 0.587f * g.z + 0.114f * bl.z;
            float g3 = 0.2989f * r.w + 0.587f * g.w + 0.114f * bl.w;
            uint2 o;
            o.x = (unsigned)f2bf(g0) | ((unsigned)f2bf(g1) << 16);
            o.y = (unsigned)f2bf(g2) | ((unsigned)f2bf(g3) << 16);
            *(uint2*)&Bs[row * 40 + cg] = o;
        }
        __syncthreads();
        short8 af[4], bfr[4];
#pragma unroll
        for (int i = 0; i < 4; ++i)
            af[i] = *(const short8*)&As[(wr + i * 16 + fr) * 40 + fk];
#pragma unroll
        for (int j = 0; j < 4; ++j)
            bfr[j] = *(const short8*)&Bs[(wc + j * 16 + fr) * 40 + fk];
#pragma unroll
        for (int i = 0; i < 4; ++i)
#pragma unroll
            for (int j = 0; j < 4; ++j)
                acc[i][j] = __builtin_amdgcn_mfma_f32_16x16x32_bf16(
                    af[i], bfr[j], acc[i][j], 0, 0, 0);
        __syncthreads();
    }

    u16* dst = ((r0 < 256) ? Tt_re : Tt_im) + (size_t)b * 65536
             + (size_t)(r0 & 255) * 256;
    int rq = (lane >> 4) << 2;
#pragma unroll
    for (int i = 0; i < 4; ++i)
#pragma unroll
        for (int j = 0; j < 4; ++j) {
            int col = h0 + wc + j * 16 + fr;
#pragma unroll
            for (int reg = 0; reg < 4; ++reg) {
                int row = wr + i * 16 + rq + reg;
                dst[(size_t)row * 256 + col] = f2bf(acc[i][j][reg]);
            }
        }
}

// ---------------------------------------------------------------------------
// s2f: stage-2 GEMM (blocks [0,1024)) + row128 (blocks [1024,1152)),
// plus last-block-per-batch fused finalize (threadfence + atomic counter:
// the 9th finisher for batch b computes out[b]; no spinning -> no deadlock).
// ---------------------------------------------------------------------------
__global__ __launch_bounds__(256) void s2f(const u16* __restrict__ A1,
                                           const float* __restrict__ M_re,
                                           const u16* __restrict__ Tt_re,
                                           const u16* __restrict__ Tt_im,
                                           float* __restrict__ tbin,
                                           const float* __restrict__ nrpart,
                                           const float* __restrict__ w,
                                           const float* __restrict__ bias,
                                           float* __restrict__ out,
                                           int* __restrict__ cnt) {
    __shared__ u16 Ar[64 * 40], Ai[64 * 40], Br[64 * 40], Bi[64 * 40];
    __shared__ float sbins[NBINS];
    __shared__ float sM[256];
    __shared__ float prof[NBINS];
    __shared__ float smn, smx, ssum;
    __shared__ int sdone;
    int blk = blockIdx.x;
    int t = threadIdx.x;
    int b;

    if (blk >= 1024) {           // ---- row128 ----
        b = blk - 1024;
        sM[t] = M_re[128 * 256 + t];
        __syncthreads();
        if (t <= 128) {
            const u16* pr = Tt_re + (size_t)b * 65536 + (size_t)t * 256;
            const u16* pi = Tt_im + (size_t)b * 65536 + (size_t)t * 256;
            float re = 0.0f, im = 0.0f;
            for (int h = 0; h < 256; h += 8) {
                uint4 vr = *(const uint4*)(pr + h);
                uint4 vi = *(const uint4*)(pi + h);
                unsigned wr[4] = {vr.x, vr.y, vr.z, vr.w};
                unsigned wi[4] = {vi.x, vi.y, vi.z, vi.w};
#pragma unroll
                for (int q = 0; q < 4; ++q) {
                    re = fmaf(sM[h + 2 * q], bf2f((u16)(wr[q] & 0xffff)), re);
                    re = fmaf(sM[h + 2 * q + 1], bf2f((u16)(wr[q] >> 16)), re);
                    im = fmaf(sM[h + 2 * q], bf2f((u16)(wi[q] & 0xffff)), im);
                    im = fmaf(sM[h + 2 * q + 1], bf2f((u16)(wi[q] >> 16)), im);
                }
            }
            re += 1e-8f; im += 1e-8f;
            float mag = __logf(sqrtf(re * re + im * im + 1e-10f) + 1e-10f);
            float wj = (t == 0 || t == 128) ? 1.0f : 2.0f;
            int dx = (t < 128) ? t : t - 256;
            int bin = radial_bin(dx, -128);
            atomicAdd(&tbin[b * NBINS + bin], wj * mag);
        }
    } else {
        // ---- s2 GEMM ----
        b = blk >> 3;
        int u0 = ((blk >> 2) & 1) * 64;
        int j0 = (blk & 3) * 64;
        int lane = t & 63, wv = t >> 6;
        int wu = (wv >> 1) * 32;
        int wj = (wv & 1) * 32;
        int fr = lane & 15;
        int fk = (lane >> 4) << 3;

        for (int i = t; i < NBINS; i += 256) sbins[i] = 0.0f;

        f32x4 accr[2][2], acci[2][2];
#pragma unroll
        for (int i = 0; i < 2; ++i)
#pragma unroll
            for (int j = 0; j < 2; ++j) {
                accr[i][j] = (f32x4){0.f, 0.f, 0.f, 0.f};
                acci[i][j] = (f32x4){0.f, 0.f, 0.f, 0.f};
            }

        const u16* Apr = A1 + (size_t)u0 * 256;
        const u16* Api = A1 + (size_t)(256 + u0) * 256;
        const u16* Tr = Tt_re + (size_t)b * 65536 + (size_t)j0 * 256;
        const u16* Ti = Tt_im + (size_t)b * 65536 + (size_t)j0 * 256;

        int lrow = t >> 2, loff = (t & 3) << 3;

        for (int kk = 0; kk < 256; kk += 32) {
            *(uint4*)&Ar[lrow * 40 + loff] =
                *(const uint4*)(Apr + (size_t)lrow * 256 + kk + loff);
            *(uint4*)&Ai[lrow * 40 + loff] =
                *(const uint4*)(Api + (size_t)lrow * 256 + kk + loff);
            *(uint4*)&Br[lrow * 40 + loff] =
                *(const uint4*)(Tr + (size_t)lrow * 256 + kk + loff);
            *(uint4*)&Bi[lrow * 40 + loff] =
                *(const uint4*)(Ti + (size_t)lrow * 256 + kk + loff);
            __syncthreads();
            short8 arf[2], aif[2], naif[2], brf[2], bif[2];
#pragma unroll
            for (int i = 0; i < 2; ++i) {
                arf[i] = *(const short8*)&Ar[(wu + i * 16 + fr) * 40 + fk];
                aif[i] = *(const short8*)&Ai[(wu + i * 16 + fr) * 40 + fk];
                naif[i] = negbf(aif[i]);
            }
#pragma unroll
            for (int j = 0; j < 2; ++j) {
                brf[j] = *(const short8*)&Br[(wj + j * 16 + fr) * 40 + fk];
                bif[j] = *(const short8*)&Bi[(wj + j * 16 + fr) * 40 + fk];
            }
#pragma unroll
            for (int i = 0; i < 2; ++i)
#pragma unroll
                for (int j = 0; j < 2; ++j) {
                    accr[i][j] = __builtin_amdgcn_mfma_f32_16x16x32_bf16(
                        arf[i], brf[j], accr[i][j], 0, 0, 0);
                    accr[i][j] = __builtin_amdgcn_mfma_f32_16x16x32_bf16(
                        naif[i], bif[j], accr[i][j], 0, 0, 0);
                    acci[i][j] = __builtin_amdgcn_mfma_f32_16x16x32_bf16(
                        arf[i], bif[j], acci[i][j], 0, 0, 0);
                    acci[i][j] = __builtin_amdgcn_mfma_f32_16x16x32_bf16(
                        aif[i], brf[j], acci[i][j], 0, 0, 0);
                }
            __syncthreads();
        }

        int rq = (lane >> 4) << 2;
#pragma unroll
        for (int i = 0; i < 2; ++i)
#pragma unroll
            for (int j = 0; j < 2; ++j) {
                int v = j0 + wj + j * 16 + fr;
                int dx = (v < 128) ? v : v - 256;
                int dx2 = dx * dx;
#pragma unroll
                for (int reg = 0; reg < 4; ++reg) {
                    int u = u0 + wu + i * 16 + rq + reg;   // 0..127
                    float wrow = (u == 0) ? 1.0f : 2.0f;
                    int bin = (int)sqrtf((float)(dx2 + u * u));
                    float re = accr[i][j][reg] + 1e-8f;
                    float im = acci[i][j][reg] + 1e-8f;
                    float mag = __logf(sqrtf(re * re + im * im + 1e-10f) + 1e-10f);
                    atomicAdd(&sbins[bin], wrow * mag);
                }
            }
        __syncthreads();
        for (int i = t; i < NBINS; i += 256)
            atomicAdd(&tbin[b * NBINS + i], sbins[i]);
    }

    // ---- last-block-per-batch finalize (9 contributors per batch) ----
    __threadfence();             // make our tbin atomics device-visible
    __syncthreads();             // order thread0's counter after all fences
    if (t == 0) sdone = atomicAdd(&cnt[b], 1);
    __syncthreads();
    if (sdone != 8) return;

    if (t < NBINS) {
        const float4* p = (const float4*)(nrpart + t * 256);
        float4 a = {0.f, 0.f, 0.f, 0.f};
        for (int i = 0; i < 64; ++i) {
            float4 v = p[i];
            a.x += v.x; a.y += v.y; a.z += v.z; a.w += v.w;
        }
        float nr = (a.x + a.y) + (a.z + a.w);
        float tb = __hip_atomic_load(&tbin[b * NBINS + t], __ATOMIC_RELAXED,
                                     __HIP_MEMORY_SCOPE_AGENT);
        prof[t] = tb / (nr + 1e-10f);
    }
    __syncthreads();
    if (t == 0) {
        float mn = prof[1], mx = prof[1];
        for (int i = 2; i <= 179; ++i) {
            float p = prof[i];
            mn = fminf(mn, p);
            mx = fmaxf(mx, p);
        }
        smn = mn; smx = mx; ssum = 0.0f;
    }
    __syncthreads();
    if (t < 90) {
        float denom = smx - smn;
        float v = (prof[90 + t] - smn) / denom;
        if (v != v) v = 0.0f;
        atomicAdd(&ssum, v * w[t]);
    }
    __syncthreads();
    if (t == 0) out[b] = ssum + bias[0];
}

// ---------------------------------------------------------------------------
extern "C" void kernel_launch(void* const* d_in, const int* in_sizes, int n_in,
                              void* d_out, int out_size, void* d_ws, size_t ws_size,
                              hipStream_t stream) {
    const float* x = (const float*)d_in[0];     // (128,3,256,256)
    const float* w = (const float*)d_in[1];     // (1,90)
    const float* bias = (const float*)d_in[2];  // (1,)
    float* out = (float*)d_out;                 // (128,1)

    float* M_re = (float*)d_ws;                    // 65536 f
    float* M_im = M_re + 65536;                    // 65536 f
    u16* A1 = (u16*)(M_im + 65536);                // 512*256 u16
    u16* Tt_re = A1 + 131072;                      // 128*65536 u16
    u16* Tt_im = Tt_re + (size_t)NB * 65536;       // 128*65536 u16
    float* tbin = (float*)(Tt_im + (size_t)NB * 65536);   // NB*NBINS f
    float* nrpart = tbin + NB * NBINS;             // NBINS*256 f [bin][row]
    int* cnt = (int*)(nrpart + NBINS * 256);       // NB ints

    prep<<<544, 256, 0, stream>>>(M_re, M_im, A1, nrpart, tbin, cnt);
    s1<<<dim3(2, 4, NB), 256, 0, stream>>>(x, A1, Tt_re, Tt_im);
    s2f<<<1152, 256, 0, stream>>>(A1, M_re, Tt_re, Tt_im, tbin, nrpart,
                                  w, bias, out, cnt);
}

// Round 9
// 254.733 us; speedup vs baseline: 1.2481x; 1.2481x over previous
//
#include <hip/hip_runtime.h>
#include <math.h>

#define NBINS 182
#define NB 128   // batch

typedef unsigned short u16;
typedef __attribute__((ext_vector_type(8))) short short8;   // 8 bf16 (4 VGPRs)
typedef __attribute__((ext_vector_type(4))) float f32x4;    // MFMA accumulator

__device__ __forceinline__ u16 f2bf(float f) {
    union { float f; unsigned u; } v; v.f = f;
    unsigned r = v.u + 0x7FFF + ((v.u >> 16) & 1);   // RNE
    return (u16)(r >> 16);
}
__device__ __forceinline__ float bf2f(u16 u) {
    union { unsigned u; float f; } v; v.u = ((unsigned)u) << 16;
    return v.f;
}
__device__ __forceinline__ short8 negbf(short8 v) {
    short8 r;
#pragma unroll
    for (int i = 0; i < 8; ++i) r[i] = v[i] ^ (short)0x8000;
    return r;
}

// (int)sqrtf is EXACT here: d2 <= 32768, non-square integers are >= 2.7e-3
// from an integer sqrt (350x float ulp at 181).
__device__ __forceinline__ int radial_bin(int dx, int dy) {
    return (int)sqrtf((float)(dx * dx + dy * dy));
}

// ---------------------------------------------------------------------------
// prep: small setup launch.
//   [0,256)    build_M row j (fp64 accum -> M fp32 + A1 bf16)
//   [256,512)  nr partial histogram -> nrpart[bin][row] (transposed)
//   [512,544)  zero tbin
// ---------------------------------------------------------------------------
__global__ __launch_bounds__(256) void prep(float* __restrict__ M_re,
                                            float* __restrict__ M_im,
                                            u16* __restrict__ A1,
                                            float* __restrict__ nrpart,
                                            float* __restrict__ tbin) {
    __shared__ double ctab[1024];
    __shared__ double stab[1024];
    __shared__ float s[NBINS];
    int blk = blockIdx.x;
    int t = threadIdx.x;

    if (blk < 256) {             // ---- build_M ----
        for (int i = t; i < 1024; i += 256) {
            double a = 3.14159265358979323846 * (double)i / 512.0;
            ctab[i] = cos(a);
            stab[i] = sin(a);
        }
        __syncthreads();
        int j = blk;
        int w = t;
        double re = 0.0, im = 0.0;
        int tw = 2 * w + 1;
        for (int k = 0; k < 256; ++k) {
            int e = (4 * j * k) & 1023;
            int m = (tw * k) & 1023;
            double cw = 2.0 * ctab[m];
            re += ctab[e] * cw;
            im -= stab[e] * cw;
        }
        M_re[j * 256 + w] = (float)re;
        M_im[j * 256 + w] = (float)im;
        A1[j * 256 + w] = f2bf((float)re);
        A1[(j + 256) * 256 + w] = f2bf((float)im);
    } else if (blk < 512) {      // ---- nr partial histogram, row i ----
        int i = blk - 256;
        if (t < NBINS) s[t] = 0.0f;
        __syncthreads();
        int bin = radial_bin(t - 128, i - 128);
        atomicAdd(&s[bin], 1.0f);
        __syncthreads();
        if (t < NBINS) nrpart[t * 256 + i] = s[t];   // [bin][row]
    } else {                     // ---- zero tbin ----
        int idx = (blk - 512) * 256 + t;
        for (int i = idx; i < NB * NBINS; i += 32 * 256) tbin[i] = 0.0f;
    }
}

// ---------------------------------------------------------------------------
// Stage 1 (MFMA, gray fused): C[r][h] = sum_w A1[r,w] * luma(x)[b,h,w]
// r in [0,512): r<256 -> Tt_re row r, else Tt_im row r-256. Output bf16.
// Block: 128x128 tile, 256 thr, wave = 64x64 (4x4 of 16x16x32). K=256, BK=32.
// B-staging computes luma from the 3 x-channels on the fly (x is L3-resident;
// no G materialization).
// ---------------------------------------------------------------------------
__global__ __launch_bounds__(256) void s1(const float* __restrict__ x,
                                          const u16* __restrict__ A1,
                                          u16* __restrict__ Tt_re,
                                          u16* __restrict__ Tt_im) {
    __shared__ u16 As[128 * 40];   // row stride 40 (16B-aligned, conflict-free)
    __shared__ u16 Bs[128 * 40];
    int b = blockIdx.z;
    int r0 = blockIdx.y * 128;    // 0,128,256,384
    int h0 = blockIdx.x * 128;    // 0,128
    int t = threadIdx.x;
    int lane = t & 63, wv = t >> 6;
    int wr = (wv >> 1) * 64;
    int wc = (wv & 1) * 64;
    int fr = lane & 15;
    int fk = (lane >> 4) << 3;

    f32x4 acc[4][4];
#pragma unroll
    for (int i = 0; i < 4; ++i)
#pragma unroll
        for (int j = 0; j < 4; ++j) acc[i][j] = (f32x4){0.f, 0.f, 0.f, 0.f};

    const u16* Ap = A1 + (size_t)r0 * 256;
    const float* xb = x + (size_t)b * 196608 + (size_t)h0 * 256;

    for (int kk = 0; kk < 256; kk += 32) {
        // A tile: 128 rows x 32 cols bf16
#pragma unroll
        for (int c = t; c < 512; c += 256) {
            int row = c >> 2, off = (c & 3) << 3;
            *(uint4*)&As[row * 40 + off] =
                *(const uint4*)(Ap + (size_t)row * 256 + kk + off);
        }
        // B tile: luma of x, 128 rows x 32 cols -> bf16
#pragma unroll
        for (int it = 0; it < 4; ++it) {
            int id = t + it * 256;          // 0..1023
            int row = id >> 3;              // 0..127
            int cg = (id & 7) * 4;          // 0,4,..,28
            const float* p = xb + (size_t)row * 256 + kk + cg;
            float4 r = *(const float4*)p;
            float4 g = *(const float4*)(p + 65536);
            float4 bl = *(const float4*)(p + 131072);
            float g0 = 0.2989f * r.x + 0.587f * g.x + 0.114f * bl.x;
            float g1 = 0.2989f * r.y + 0.587f * g.y + 0.114f * bl.y;
            float g2 = 0.2989f * r.z + 0.587f * g.z + 0.114f * bl.z;
            float g3 = 0.2989f * r.w + 0.587f * g.w + 0.114f * bl.w;
            uint2 o;
            o.x = (unsigned)f2bf(g0) | ((unsigned)f2bf(g1) << 16);
            o.y = (unsigned)f2bf(g2) | ((unsigned)f2bf(g3) << 16);
            *(uint2*)&Bs[row * 40 + cg] = o;
        }
        __syncthreads();
        short8 af[4], bfr[4];
#pragma unroll
        for (int i = 0; i < 4; ++i)
            af[i] = *(const short8*)&As[(wr + i * 16 + fr) * 40 + fk];
#pragma unroll
        for (int j = 0; j < 4; ++j)
            bfr[j] = *(const short8*)&Bs[(wc + j * 16 + fr) * 40 + fk];
#pragma unroll
        for (int i = 0; i < 4; ++i)
#pragma unroll
            for (int j = 0; j < 4; ++j)
                acc[i][j] = __builtin_amdgcn_mfma_f32_16x16x32_bf16(
                    af[i], bfr[j], acc[i][j], 0, 0, 0);
        __syncthreads();
    }

    u16* dst = ((r0 < 256) ? Tt_re : Tt_im) + (size_t)b * 65536
             + (size_t)(r0 & 255) * 256;
    int rq = (lane >> 4) << 2;
#pragma unroll
    for (int i = 0; i < 4; ++i)
#pragma unroll
        for (int j = 0; j < 4; ++j) {
            int col = h0 + wc + j * 16 + fr;
#pragma unroll
            for (int reg = 0; reg < 4; ++reg) {
                int row = wr + i * 16 + rq + reg;
                dst[(size_t)row * 256 + col] = f2bf(acc[i][j][reg]);
            }
        }
}

// ---------------------------------------------------------------------------
// s2f: fused stage-2 GEMM (blocks [0,1024)) + row128 (blocks [1024,1152)).
// NO device-scope fences here (R8 lesson: __threadfence in 1152 blocks
// = serialized L2 drains on 8-XCD part, +100 us).
// ---------------------------------------------------------------------------
__global__ __launch_bounds__(256) void s2f(const u16* __restrict__ A1,
                                           const float* __restrict__ M_re,
                                           const u16* __restrict__ Tt_re,
                                           const u16* __restrict__ Tt_im,
                                           float* __restrict__ tbin) {
    __shared__ u16 Ar[64 * 40], Ai[64 * 40], Br[64 * 40], Bi[64 * 40];
    __shared__ float sbins[NBINS];
    __shared__ float sM[256];
    int blk = blockIdx.x;
    int t = threadIdx.x;

    if (blk >= 1024) {           // ---- row128 ----
        int b = blk - 1024;
        sM[t] = M_re[128 * 256 + t];
        __syncthreads();
        if (t > 128) return;
        const u16* pr = Tt_re + (size_t)b * 65536 + (size_t)t * 256;
        const u16* pi = Tt_im + (size_t)b * 65536 + (size_t)t * 256;
        float re = 0.0f, im = 0.0f;
        for (int h = 0; h < 256; h += 8) {
            uint4 vr = *(const uint4*)(pr + h);
            uint4 vi = *(const uint4*)(pi + h);
            unsigned wr[4] = {vr.x, vr.y, vr.z, vr.w};
            unsigned wi[4] = {vi.x, vi.y, vi.z, vi.w};
#pragma unroll
            for (int q = 0; q < 4; ++q) {
                re = fmaf(sM[h + 2 * q], bf2f((u16)(wr[q] & 0xffff)), re);
                re = fmaf(sM[h + 2 * q + 1], bf2f((u16)(wr[q] >> 16)), re);
                im = fmaf(sM[h + 2 * q], bf2f((u16)(wi[q] & 0xffff)), im);
                im = fmaf(sM[h + 2 * q + 1], bf2f((u16)(wi[q] >> 16)), im);
            }
        }
        re += 1e-8f; im += 1e-8f;
        float mag = __logf(sqrtf(re * re + im * im + 1e-10f) + 1e-10f);
        float wj = (t == 0 || t == 128) ? 1.0f : 2.0f;
        int dx = (t < 128) ? t : t - 256;
        int bin = radial_bin(dx, -128);
        atomicAdd(&tbin[b * NBINS + bin], wj * mag);
        return;
    }

    // ---- s2 GEMM ----
    int b = blk >> 3;
    int u0 = ((blk >> 2) & 1) * 64;
    int j0 = (blk & 3) * 64;
    int lane = t & 63, wv = t >> 6;
    int wu = (wv >> 1) * 32;
    int wj = (wv & 1) * 32;
    int fr = lane & 15;
    int fk = (lane >> 4) << 3;

    for (int i = t; i < NBINS; i += 256) sbins[i] = 0.0f;

    f32x4 accr[2][2], acci[2][2];
#pragma unroll
    for (int i = 0; i < 2; ++i)
#pragma unroll
        for (int j = 0; j < 2; ++j) {
            accr[i][j] = (f32x4){0.f, 0.f, 0.f, 0.f};
            acci[i][j] = (f32x4){0.f, 0.f, 0.f, 0.f};
        }

    const u16* Apr = A1 + (size_t)u0 * 256;
    const u16* Api = A1 + (size_t)(256 + u0) * 256;
    const u16* Tr = Tt_re + (size_t)b * 65536 + (size_t)j0 * 256;
    const u16* Ti = Tt_im + (size_t)b * 65536 + (size_t)j0 * 256;

    int lrow = t >> 2, loff = (t & 3) << 3;

    for (int kk = 0; kk < 256; kk += 32) {
        *(uint4*)&Ar[lrow * 40 + loff] =
            *(const uint4*)(Apr + (size_t)lrow * 256 + kk + loff);
        *(uint4*)&Ai[lrow * 40 + loff] =
            *(const uint4*)(Api + (size_t)lrow * 256 + kk + loff);
        *(uint4*)&Br[lrow * 40 + loff] =
            *(const uint4*)(Tr + (size_t)lrow * 256 + kk + loff);
        *(uint4*)&Bi[lrow * 40 + loff] =
            *(const uint4*)(Ti + (size_t)lrow * 256 + kk + loff);
        __syncthreads();
        short8 arf[2], aif[2], naif[2], brf[2], bif[2];
#pragma unroll
        for (int i = 0; i < 2; ++i) {
            arf[i] = *(const short8*)&Ar[(wu + i * 16 + fr) * 40 + fk];
            aif[i] = *(const short8*)&Ai[(wu + i * 16 + fr) * 40 + fk];
            naif[i] = negbf(aif[i]);
        }
#pragma unroll
        for (int j = 0; j < 2; ++j) {
            brf[j] = *(const short8*)&Br[(wj + j * 16 + fr) * 40 + fk];
            bif[j] = *(const short8*)&Bi[(wj + j * 16 + fr) * 40 + fk];
        }
#pragma unroll
        for (int i = 0; i < 2; ++i)
#pragma unroll
            for (int j = 0; j < 2; ++j) {
                accr[i][j] = __builtin_amdgcn_mfma_f32_16x16x32_bf16(
                    arf[i], brf[j], accr[i][j], 0, 0, 0);
                accr[i][j] = __builtin_amdgcn_mfma_f32_16x16x32_bf16(
                    naif[i], bif[j], accr[i][j], 0, 0, 0);
                acci[i][j] = __builtin_amdgcn_mfma_f32_16x16x32_bf16(
                    arf[i], bif[j], acci[i][j], 0, 0, 0);
                acci[i][j] = __builtin_amdgcn_mfma_f32_16x16x32_bf16(
                    aif[i], brf[j], acci[i][j], 0, 0, 0);
            }
        __syncthreads();
    }

    int rq = (lane >> 4) << 2;
#pragma unroll
    for (int i = 0; i < 2; ++i)
#pragma unroll
        for (int j = 0; j < 2; ++j) {
            int v = j0 + wj + j * 16 + fr;
            int dx = (v < 128) ? v : v - 256;
            int dx2 = dx * dx;
#pragma unroll
            for (int reg = 0; reg < 4; ++reg) {
                int u = u0 + wu + i * 16 + rq + reg;   // 0..127
                float wrow = (u == 0) ? 1.0f : 2.0f;
                int bin = (int)sqrtf((float)(dx2 + u * u));
                float re = accr[i][j][reg] + 1e-8f;
                float im = acci[i][j][reg] + 1e-8f;
                float mag = __logf(sqrtf(re * re + im * im + 1e-10f) + 1e-10f);
                atomicAdd(&sbins[bin], wrow * mag);
            }
        }
    __syncthreads();
    for (int i = t; i < NBINS; i += 256)
        atomicAdd(&tbin[b * NBINS + i], sbins[i]);
}

// ---------------------------------------------------------------------------
// Finalize: nr[t] = row-sum of nrpart[t][*] (contiguous); prof = tbin/nr;
// min-max over bins 1..179; dot bins 90..179 with w.
// ---------------------------------------------------------------------------
__global__ __launch_bounds__(192) void finalize(const float* __restrict__ tbin,
                                                const float* __restrict__ nrpart,
                                                const float* __restrict__ w,
                                                const float* __restrict__ bias,
                                                float* __restrict__ out) {
    __shared__ float prof[NBINS];
    __shared__ float smn, smx, ssum;
    int b = blockIdx.x;
    int t = threadIdx.x;
    if (t < NBINS) {
        const float4* p = (const float4*)(nrpart + t * 256);
        float4 a = {0.f, 0.f, 0.f, 0.f};
        for (int i = 0; i < 64; ++i) {
            float4 v = p[i];
            a.x += v.x; a.y += v.y; a.z += v.z; a.w += v.w;
        }
        float nr = (a.x + a.y) + (a.z + a.w);
        prof[t] = tbin[b * NBINS + t] / (nr + 1e-10f);
    }
    __syncthreads();
    if (t == 0) {
        float mn = prof[1], mx = prof[1];
        for (int i = 2; i <= 179; ++i) {
            float p = prof[i];
            mn = fminf(mn, p);
            mx = fmaxf(mx, p);
        }
        smn = mn; smx = mx; ssum = 0.0f;
    }
    __syncthreads();
    if (t < 90) {
        float denom = smx - smn;
        float v = (prof[90 + t] - smn) / denom;
        if (v != v) v = 0.0f;
        atomicAdd(&ssum, v * w[t]);
    }
    __syncthreads();
    if (t == 0) out[b] = ssum + bias[0];
}

// ---------------------------------------------------------------------------
extern "C" void kernel_launch(void* const* d_in, const int* in_sizes, int n_in,
                              void* d_out, int out_size, void* d_ws, size_t ws_size,
                              hipStream_t stream) {
    const float* x = (const float*)d_in[0];     // (128,3,256,256)
    const float* w = (const float*)d_in[1];     // (1,90)
    const float* bias = (const float*)d_in[2];  // (1,)
    float* out = (float*)d_out;                 // (128,1)

    float* M_re = (float*)d_ws;                    // 65536 f
    float* M_im = M_re + 65536;                    // 65536 f
    u16* A1 = (u16*)(M_im + 65536);                // 512*256 u16
    u16* Tt_re = A1 + 131072;                      // 128*65536 u16
    u16* Tt_im = Tt_re + (size_t)NB * 65536;       // 128*65536 u16
    float* tbin = (float*)(Tt_im + (size_t)NB * 65536);   // NB*NBINS f
    float* nrpart = tbin + NB * NBINS;             // NBINS*256 f [bin][row]

    prep<<<544, 256, 0, stream>>>(M_re, M_im, A1, nrpart, tbin);
    s1<<<dim3(2, 4, NB), 256, 0, stream>>>(x, A1, Tt_re, Tt_im);
    s2f<<<1152, 256, 0, stream>>>(A1, M_re, Tt_re, Tt_im, tbin);
    finalize<<<NB, 192, 0, stream>>>(tbin, nrpart, w, bias, out);
}

// Round 10
// 230.542 us; speedup vs baseline: 1.3791x; 1.1049x over previous
//
#include <hip/hip_runtime.h>
#include <math.h>

#define NBINS 182
#define NB 128   // batch

typedef unsigned short u16;
typedef __attribute__((ext_vector_type(8))) short short8;   // 8 bf16 (4 VGPRs)
typedef __attribute__((ext_vector_type(4))) float f32x4;    // MFMA accumulator

__device__ __forceinline__ u16 f2bf(float f) {
    union { float f; unsigned u; } v; v.f = f;
    unsigned r = v.u + 0x7FFF + ((v.u >> 16) & 1);   // RNE
    return (u16)(r >> 16);
}
__device__ __forceinline__ float bf2f(u16 u) {
    union { unsigned u; float f; } v; v.u = ((unsigned)u) << 16;
    return v.f;
}
__device__ __forceinline__ short8 negbf(short8 v) {
    short8 r;
#pragma unroll
    for (int i = 0; i < 8; ++i) r[i] = v[i] ^ (short)0x8000;
    return r;
}

// (int)sqrtf is EXACT here: d2 <= 32768, non-square integers are >= 2.7e-3
// from an integer sqrt (350x float ulp at 181).
__device__ __forceinline__ int radial_bin(int dx, int dy) {
    return (int)sqrtf((float)(dx * dx + dy * dy));
}

// ---------------------------------------------------------------------------
// prep: one launch, 4 jobs by block range. Latency-heavy blocks first.
//   [0,256)     build_M row j (fp64 accum -> M fp32 + A1 bf16)
//   [256,512)   nr partial histogram -> nrpart[bin][row] (transposed)
//   [512,544)   zero tbin
//   [544,4640)  gray one-shot: 8 px/thread, 6 independent 16B loads, no loop
//               (R6's 4px grid-stride ran at 1 TB/s, latency-bound)
// ---------------------------------------------------------------------------
__global__ __launch_bounds__(256) void prep(const float* __restrict__ x,
                                            u16* __restrict__ G,
                                            float* __restrict__ M_re,
                                            float* __restrict__ M_im,
                                            u16* __restrict__ A1,
                                            float* __restrict__ nrpart,
                                            float* __restrict__ tbin) {
    __shared__ double ctab[1024];
    __shared__ double stab[1024];
    __shared__ float s[NBINS];
    int blk = blockIdx.x;
    int t = threadIdx.x;

    if (blk < 256) {             // ---- build_M ----
        for (int i = t; i < 1024; i += 256) {
            double a = 3.14159265358979323846 * (double)i / 512.0;
            ctab[i] = cos(a);
            stab[i] = sin(a);
        }
        __syncthreads();
        int j = blk;
        int w = t;
        double re = 0.0, im = 0.0;
        int tw = 2 * w + 1;
        for (int k = 0; k < 256; ++k) {
            int e = (4 * j * k) & 1023;
            int m = (tw * k) & 1023;
            double cw = 2.0 * ctab[m];
            re += ctab[e] * cw;
            im -= stab[e] * cw;
        }
        M_re[j * 256 + w] = (float)re;
        M_im[j * 256 + w] = (float)im;
        A1[j * 256 + w] = f2bf((float)re);
        A1[(j + 256) * 256 + w] = f2bf((float)im);
    } else if (blk < 512) {      // ---- nr partial histogram, row i ----
        int i = blk - 256;
        if (t < NBINS) s[t] = 0.0f;
        __syncthreads();
        int bin = radial_bin(t - 128, i - 128);
        atomicAdd(&s[bin], 1.0f);
        __syncthreads();
        if (t < NBINS) nrpart[t * 256 + i] = s[t];   // [bin][row]
    } else if (blk < 544) {      // ---- zero tbin ----
        int idx = (blk - 512) * 256 + t;
        for (int i = idx; i < NB * NBINS; i += 32 * 256) tbin[i] = 0.0f;
    } else {                     // ---- gray: 8 px/thread, one shot ----
        int tid = (blk - 544) * 256 + t;          // 0..1048575
        int idx = tid * 8;                        // same row: 65536 % 8 == 0
        int b = idx >> 16;
        int rem = idx & 65535;
        const float* p = x + (size_t)b * 196608 + rem;
        float4 r0 = *(const float4*)p;
        float4 r1 = *(const float4*)(p + 4);
        float4 g0 = *(const float4*)(p + 65536);
        float4 g1 = *(const float4*)(p + 65540);
        float4 b0 = *(const float4*)(p + 131072);
        float4 b1 = *(const float4*)(p + 131076);
        uint4 o;
        o.x = (unsigned)f2bf(0.2989f * r0.x + 0.587f * g0.x + 0.114f * b0.x)
            | ((unsigned)f2bf(0.2989f * r0.y + 0.587f * g0.y + 0.114f * b0.y) << 16);
        o.y = (unsigned)f2bf(0.2989f * r0.z + 0.587f * g0.z + 0.114f * b0.z)
            | ((unsigned)f2bf(0.2989f * r0.w + 0.587f * g0.w + 0.114f * b0.w) << 16);
        o.z = (unsigned)f2bf(0.2989f * r1.x + 0.587f * g1.x + 0.114f * b1.x)
            | ((unsigned)f2bf(0.2989f * r1.y + 0.587f * g1.y + 0.114f * b1.y) << 16);
        o.w = (unsigned)f2bf(0.2989f * r1.z + 0.587f * g1.z + 0.114f * b1.z)
            | ((unsigned)f2bf(0.2989f * r1.w + 0.587f * g1.w + 0.114f * b1.w) << 16);
        *(uint4*)(G + idx) = o;
    }
}

// ---------------------------------------------------------------------------
// Stage 1 (MFMA): C[r][h] = sum_w A1[r,w] * G[b,h,w]   (gemm_bt, bf16 in)
// r in [0,512): r<256 -> Tt_re row r, else Tt_im row r-256. Output bf16.
// Block: 128x128 tile, 256 thr, wave = 64x64 (4x4 of 16x16x32). K=256, BK=32.
// ---------------------------------------------------------------------------
__global__ __launch_bounds__(256) void s1(const u16* __restrict__ A1,
                                          const u16* __restrict__ G,
                                          u16* __restrict__ Tt_re,
                                          u16* __restrict__ Tt_im) {
    __shared__ u16 As[128 * 40];   // row stride 40 (16B-aligned, conflict-free)
    __shared__ u16 Bs[128 * 40];
    int b = blockIdx.z;
    int r0 = blockIdx.y * 128;    // 0,128,256,384
    int h0 = blockIdx.x * 128;    // 0,128
    int t = threadIdx.x;
    int lane = t & 63, wv = t >> 6;
    int wr = (wv >> 1) * 64;
    int wc = (wv & 1) * 64;
    int fr = lane & 15;
    int fk = (lane >> 4) << 3;

    f32x4 acc[4][4];
#pragma unroll
    for (int i = 0; i < 4; ++i)
#pragma unroll
        for (int j = 0; j < 4; ++j) acc[i][j] = (f32x4){0.f, 0.f, 0.f, 0.f};

    const u16* Ap = A1 + (size_t)r0 * 256;
    const u16* Gp = G + (size_t)b * 65536 + (size_t)h0 * 256;

    for (int kk = 0; kk < 256; kk += 32) {
#pragma unroll
        for (int c = t; c < 512; c += 256) {
            int row = c >> 2, off = (c & 3) << 3;
            *(uint4*)&As[row * 40 + off] =
                *(const uint4*)(Ap + (size_t)row * 256 + kk + off);
            *(uint4*)&Bs[row * 40 + off] =
                *(const uint4*)(Gp + (size_t)row * 256 + kk + off);
        }
        __syncthreads();
        short8 af[4], bfr[4];
#pragma unroll
        for (int i = 0; i < 4; ++i)
            af[i] = *(const short8*)&As[(wr + i * 16 + fr) * 40 + fk];
#pragma unroll
        for (int j = 0; j < 4; ++j)
            bfr[j] = *(const short8*)&Bs[(wc + j * 16 + fr) * 40 + fk];
#pragma unroll
        for (int i = 0; i < 4; ++i)
#pragma unroll
            for (int j = 0; j < 4; ++j)
                acc[i][j] = __builtin_amdgcn_mfma_f32_16x16x32_bf16(
                    af[i], bfr[j], acc[i][j], 0, 0, 0);
        __syncthreads();
    }

    u16* dst = ((r0 < 256) ? Tt_re : Tt_im) + (size_t)b * 65536
             + (size_t)(r0 & 255) * 256;
    int rq = (lane >> 4) << 2;
#pragma unroll
    for (int i = 0; i < 4; ++i)
#pragma unroll
        for (int j = 0; j < 4; ++j) {
            int col = h0 + wc + j * 16 + fr;
#pragma unroll
            for (int reg = 0; reg < 4; ++reg) {
                int row = wr + i * 16 + rq + reg;
                dst[(size_t)row * 256 + col] = f2bf(acc[i][j][reg]);
            }
        }
}

// ---------------------------------------------------------------------------
// s2f: fused stage-2 GEMM (blocks [0,1024)) + row128 (blocks [1024,1152)).
// NO device-scope fences (R8 lesson: __threadfence in 1152 blocks =
// serialized cross-XCD L2 drains, +100 us).
// ---------------------------------------------------------------------------
__global__ __launch_bounds__(256) void s2f(const u16* __restrict__ A1,
                                           const float* __restrict__ M_re,
                                           const u16* __restrict__ Tt_re,
                                           const u16* __restrict__ Tt_im,
                                           float* __restrict__ tbin) {
    __shared__ u16 Ar[64 * 40], Ai[64 * 40], Br[64 * 40], Bi[64 * 40];
    __shared__ float sbins[NBINS];
    __shared__ float sM[256];
    int blk = blockIdx.x;
    int t = threadIdx.x;

    if (blk >= 1024) {           // ---- row128 ----
        int b = blk - 1024;
        sM[t] = M_re[128 * 256 + t];
        __syncthreads();
        if (t > 128) return;
        const u16* pr = Tt_re + (size_t)b * 65536 + (size_t)t * 256;
        const u16* pi = Tt_im + (size_t)b * 65536 + (size_t)t * 256;
        float re = 0.0f, im = 0.0f;
        for (int h = 0; h < 256; h += 8) {
            uint4 vr = *(const uint4*)(pr + h);
            uint4 vi = *(const uint4*)(pi + h);
            unsigned wr[4] = {vr.x, vr.y, vr.z, vr.w};
            unsigned wi[4] = {vi.x, vi.y, vi.z, vi.w};
#pragma unroll
            for (int q = 0; q < 4; ++q) {
                re = fmaf(sM[h + 2 * q], bf2f((u16)(wr[q] & 0xffff)), re);
                re = fmaf(sM[h + 2 * q + 1], bf2f((u16)(wr[q] >> 16)), re);
                im = fmaf(sM[h + 2 * q], bf2f((u16)(wi[q] & 0xffff)), im);
                im = fmaf(sM[h + 2 * q + 1], bf2f((u16)(wi[q] >> 16)), im);
            }
        }
        re += 1e-8f; im += 1e-8f;
        float mag = __logf(sqrtf(re * re + im * im + 1e-10f) + 1e-10f);
        float wj = (t == 0 || t == 128) ? 1.0f : 2.0f;
        int dx = (t < 128) ? t : t - 256;
        int bin = radial_bin(dx, -128);
        atomicAdd(&tbin[b * NBINS + bin], wj * mag);
        return;
    }

    // ---- s2 GEMM ----
    int b = blk >> 3;
    int u0 = ((blk >> 2) & 1) * 64;
    int j0 = (blk & 3) * 64;
    int lane = t & 63, wv = t >> 6;
    int wu = (wv >> 1) * 32;
    int wj = (wv & 1) * 32;
    int fr = lane & 15;
    int fk = (lane >> 4) << 3;

    for (int i = t; i < NBINS; i += 256) sbins[i] = 0.0f;

    f32x4 accr[2][2], acci[2][2];
#pragma unroll
    for (int i = 0; i < 2; ++i)
#pragma unroll
        for (int j = 0; j < 2; ++j) {
            accr[i][j] = (f32x4){0.f, 0.f, 0.f, 0.f};
            acci[i][j] = (f32x4){0.f, 0.f, 0.f, 0.f};
        }

    const u16* Apr = A1 + (size_t)u0 * 256;
    const u16* Api = A1 + (size_t)(256 + u0) * 256;
    const u16* Tr = Tt_re + (size_t)b * 65536 + (size_t)j0 * 256;
    const u16* Ti = Tt_im + (size_t)b * 65536 + (size_t)j0 * 256;

    int lrow = t >> 2, loff = (t & 3) << 3;

    for (int kk = 0; kk < 256; kk += 32) {
        *(uint4*)&Ar[lrow * 40 + loff] =
            *(const uint4*)(Apr + (size_t)lrow * 256 + kk + loff);
        *(uint4*)&Ai[lrow * 40 + loff] =
            *(const uint4*)(Api + (size_t)lrow * 256 + kk + loff);
        *(uint4*)&Br[lrow * 40 + loff] =
            *(const uint4*)(Tr + (size_t)lrow * 256 + kk + loff);
        *(uint4*)&Bi[lrow * 40 + loff] =
            *(const uint4*)(Ti + (size_t)lrow * 256 + kk + loff);
        __syncthreads();
        short8 arf[2], aif[2], naif[2], brf[2], bif[2];
#pragma unroll
        for (int i = 0; i < 2; ++i) {
            arf[i] = *(const short8*)&Ar[(wu + i * 16 + fr) * 40 + fk];
            aif[i] = *(const short8*)&Ai[(wu + i * 16 + fr) * 40 + fk];
            naif[i] = negbf(aif[i]);
        }
#pragma unroll
        for (int j = 0; j < 2; ++j) {
            brf[j] = *(const short8*)&Br[(wj + j * 16 + fr) * 40 + fk];
            bif[j] = *(const short8*)&Bi[(wj + j * 16 + fr) * 40 + fk];
        }
#pragma unroll
        for (int i = 0; i < 2; ++i)
#pragma unroll
            for (int j = 0; j < 2; ++j) {
                accr[i][j] = __builtin_amdgcn_mfma_f32_16x16x32_bf16(
                    arf[i], brf[j], accr[i][j], 0, 0, 0);
                accr[i][j] = __builtin_amdgcn_mfma_f32_16x16x32_bf16(
                    naif[i], bif[j], accr[i][j], 0, 0, 0);
                acci[i][j] = __builtin_amdgcn_mfma_f32_16x16x32_bf16(
                    arf[i], bif[j], acci[i][j], 0, 0, 0);
                acci[i][j] = __builtin_amdgcn_mfma_f32_16x16x32_bf16(
                    aif[i], brf[j], acci[i][j], 0, 0, 0);
            }
        __syncthreads();
    }

    int rq = (lane >> 4) << 2;
#pragma unroll
    for (int i = 0; i < 2; ++i)
#pragma unroll
        for (int j = 0; j < 2; ++j) {
            int v = j0 + wj + j * 16 + fr;
            int dx = (v < 128) ? v : v - 256;
            int dx2 = dx * dx;
#pragma unroll
            for (int reg = 0; reg < 4; ++reg) {
                int u = u0 + wu + i * 16 + rq + reg;   // 0..127
                float wrow = (u == 0) ? 1.0f : 2.0f;
                int bin = (int)sqrtf((float)(dx2 + u * u));
                float re = accr[i][j][reg] + 1e-8f;
                float im = acci[i][j][reg] + 1e-8f;
                float mag = __logf(sqrtf(re * re + im * im + 1e-10f) + 1e-10f);
                atomicAdd(&sbins[bin], wrow * mag);
            }
        }
    __syncthreads();
    for (int i = t; i < NBINS; i += 256)
        atomicAdd(&tbin[b * NBINS + i], sbins[i]);
}

// ---------------------------------------------------------------------------
// Finalize: nr[t] = row-sum of nrpart[t][*] (contiguous); prof = tbin/nr;
// min-max over bins 1..179; dot bins 90..179 with w.
// ---------------------------------------------------------------------------
__global__ __launch_bounds__(192) void finalize(const float* __restrict__ tbin,
                                                const float* __restrict__ nrpart,
                                                const float* __restrict__ w,
                                                const float* __restrict__ bias,
                                                float* __restrict__ out) {
    __shared__ float prof[NBINS];
    __shared__ float smn, smx, ssum;
    int b = blockIdx.x;
    int t = threadIdx.x;
    if (t < NBINS) {
        const float4* p = (const float4*)(nrpart + t * 256);
        float4 a = {0.f, 0.f, 0.f, 0.f};
        for (int i = 0; i < 64; ++i) {
            float4 v = p[i];
            a.x += v.x; a.y += v.y; a.z += v.z; a.w += v.w;
        }
        float nr = (a.x + a.y) + (a.z + a.w);
        prof[t] = tbin[b * NBINS + t] / (nr + 1e-10f);
    }
    __syncthreads();
    if (t == 0) {
        float mn = prof[1], mx = prof[1];
        for (int i = 2; i <= 179; ++i) {
            float p = prof[i];
            mn = fminf(mn, p);
            mx = fmaxf(mx, p);
        }
        smn = mn; smx = mx; ssum = 0.0f;
    }
    __syncthreads();
    if (t < 90) {
        float denom = smx - smn;
        float v = (prof[90 + t] - smn) / denom;
        if (v != v) v = 0.0f;
        atomicAdd(&ssum, v * w[t]);
    }
    __syncthreads();
    if (t == 0) out[b] = ssum + bias[0];
}

// ---------------------------------------------------------------------------
extern "C" void kernel_launch(void* const* d_in, const int* in_sizes, int n_in,
                              void* d_out, int out_size, void* d_ws, size_t ws_size,
                              hipStream_t stream) {
    const float* x = (const float*)d_in[0];     // (128,3,256,256)
    const float* w = (const float*)d_in[1];     // (1,90)
    const float* bias = (const float*)d_in[2];  // (1,)
    float* out = (float*)d_out;                 // (128,1)

    float* M_re = (float*)d_ws;                    // 65536 f
    float* M_im = M_re + 65536;                    // 65536 f
    u16* A1 = (u16*)(M_im + 65536);                // 512*256 u16
    u16* G = A1 + 131072;                          // 128*65536 u16
    u16* Tt_re = G + (size_t)NB * 65536;           // 128*65536 u16
    u16* Tt_im = Tt_re + (size_t)NB * 65536;       // 128*65536 u16
    float* tbin = (float*)(Tt_im + (size_t)NB * 65536);   // NB*NBINS f
    float* nrpart = tbin + NB * NBINS;             // NBINS*256 f [bin][row]

    prep<<<4640, 256, 0, stream>>>(x, G, M_re, M_im, A1, nrpart, tbin);
    s1<<<dim3(2, 4, NB), 256, 0, stream>>>(A1, G, Tt_re, Tt_im);
    s2f<<<1152, 256, 0, stream>>>(A1, M_re, Tt_re, Tt_im, tbin);
    finalize<<<NB, 192, 0, stream>>>(tbin, nrpart, w, bias, out);
}